// Round 8
// baseline (661.864 us; speedup 1.0000x reference)
//
#include <hip/hip_runtime.h>

#define EPS_ 1e-5f

typedef float f32x4 __attribute__((ext_vector_type(4)));
typedef short s16x8 __attribute__((ext_vector_type(8)));

static __device__ __forceinline__ short f2bf(float f) {
    unsigned u = __float_as_uint(f);
    unsigned r = (u + 0x7FFFu + ((u >> 16) & 1u)) >> 16;
    return (short)r;
}
static __device__ __forceinline__ float bf2f(short s) {
    return __uint_as_float(((unsigned)(unsigned short)s) << 16);
}

// async global->LDS, 16B per lane, wave-uniform LDS base
static __device__ __forceinline__ void gload16(const short* g, short* l) {
    __builtin_amdgcn_global_load_lds(
        (const __attribute__((address_space(1))) unsigned int*)g,
        (__attribute__((address_space(3))) unsigned int*)l, 16, 0, 0);
}

// ---------------------------------------------------------------------------
// Kernel 0: convert weight stacks to bf16 once.
// ---------------------------------------------------------------------------
__global__ __launch_bounds__(256) void prep_kernel(
    const float* __restrict__ Wq, const float* __restrict__ Wk,
    const float* __restrict__ Wv, const float* __restrict__ Wp,
    short* __restrict__ Wbf, short* __restrict__ Wpbf)
{
    int i = blockIdx.x * 256 + threadIdx.x;
    if (i < 6144) {
        float v = (i < 1024) ? Wq[i] : (i < 2048 ? Wk[i - 1024] : Wv[i - 2048]);
        Wbf[i] = f2bf(v);
    } else if (i < 6144 + 4096) {
        Wpbf[i - 6144] = f2bf(Wp[i - 6144]);
    }
}

// ---------------------------------------------------------------------------
// Kernel 1: QKV projection via MFMA + PReLU + LN(chan,freq), write bf16.
// ---------------------------------------------------------------------------
__global__ __launch_bounds__(256) void qkv_kernel(
    const float* __restrict__ x, const short* __restrict__ Wbf,
    const float* __restrict__ bq, const float* __restrict__ aq,
    const float* __restrict__ gq, const float* __restrict__ betq,
    const float* __restrict__ bk, const float* __restrict__ ak,
    const float* __restrict__ gk, const float* __restrict__ betk,
    const float* __restrict__ bv, const float* __restrict__ av,
    const float* __restrict__ gv, const float* __restrict__ betv,
    short* __restrict__ Qo, short* __restrict__ Ko, short* __restrict__ Vo)
{
    const int t = blockIdx.x;
    const int b = blockIdx.y;
    const int tid = threadIdx.x;
    const int wid = tid >> 6, lane = tid & 63;
    const int g = lane >> 4, c16 = lane & 15;
    const int f_ = tid & 63, cg = tid >> 6;

    __shared__ __align__(16) short wlds[96 * 64];
    __shared__ __align__(16) short xs[64 * 64];
    __shared__ float zs[96 * 64];
    __shared__ float stats[12][2];
    __shared__ float bias_l[96], alpha_l[96];

#pragma unroll
    for (int j = 0; j < 3; ++j) {
        int i8 = tid + 256 * j;
        int row = i8 >> 3, cb = i8 & 7;
        s16x8 v = *(const s16x8*)(Wbf + i8 * 8);
        *(s16x8*)&wlds[row * 64 + ((cb ^ (row & 7)) * 8)] = v;
    }
    if (tid < 96) {
        int row = tid; float bias, al;
        if (row < 16)      { bias = bq[row];      al = aq[row >> 2]; }
        else if (row < 32) { bias = bk[row - 16]; al = ak[(row - 16) >> 2]; }
        else               { bias = bv[row - 32]; al = av[(row - 32) >> 4]; }
        bias_l[row] = bias; alpha_l[row] = al;
    }
#pragma unroll
    for (int it = 0; it < 2; ++it) {
        int cb = cg + 4 * it, c0 = cb * 8;
        s16x8 v;
#pragma unroll
        for (int i = 0; i < 8; ++i)
            v[i] = f2bf(x[(((size_t)b * 64 + c0 + i) * 2048 + t) * 64 + f_]);
        *(s16x8*)&xs[f_ * 64 + ((cb ^ (f_ & 7)) * 8)] = v;
    }
    __syncthreads();

    const int f0 = wid * 16;
    s16x8 bfr[2];
#pragma unroll
    for (int kk = 0; kk < 2; ++kk)
        bfr[kk] = *(const s16x8*)&xs[(f0 + c16) * 64 + (((kk * 4 + g) ^ (c16 & 7)) * 8)];

    f32x4 acc[6];
#pragma unroll
    for (int rt = 0; rt < 6; ++rt) {
#pragma unroll
        for (int r = 0; r < 4; ++r) acc[rt][r] = 0.f;
#pragma unroll
        for (int kk = 0; kk < 2; ++kk) {
            s16x8 a = *(const s16x8*)&wlds[(rt * 16 + c16) * 64 + (((kk * 4 + g) ^ (c16 & 7)) * 8)];
            acc[rt] = __builtin_amdgcn_mfma_f32_16x16x32_bf16(a, bfr[kk], acc[rt], 0, 0, 0);
        }
    }

#pragma unroll
    for (int rt = 0; rt < 6; ++rt)
#pragma unroll
        for (int r = 0; r < 4; ++r) {
            int row = rt * 16 + g * 4 + r;
            float z = acc[rt][r] + bias_l[row];
            z = z >= 0.f ? z : alpha_l[row] * z;
            zs[row * 64 + f0 + c16] = z;
        }
    __syncthreads();

#pragma unroll
    for (int gi = 0; gi < 3; ++gi) {
        int grp = wid * 3 + gi;
        int base_row, n;
        if (grp < 4)      { base_row = grp * 4;             n = 256; }
        else if (grp < 8) { base_row = 16 + (grp - 4) * 4;  n = 256; }
        else              { base_row = 32 + (grp - 8) * 16; n = 1024; }
        int cnt = n >> 6;
        float s = 0.f, ss = 0.f;
        for (int i = 0; i < cnt; ++i) {
            float v = zs[(base_row + i) * 64 + lane];
            s += v; ss += v * v;
        }
#pragma unroll
        for (int msk = 32; msk >= 1; msk >>= 1) {
            s  += __shfl_xor(s, msk);
            ss += __shfl_xor(ss, msk);
        }
        if (lane == 0) {
            float mean = s / n;
            float var = ss / n - mean * mean;
            stats[grp][0] = mean;
            stats[grp][1] = rsqrtf(var + EPS_);
        }
    }
    __syncthreads();

#pragma unroll
    for (int j = 0; j < 24; ++j) {
        int row = cg + 4 * j;
        float zv = zs[row * 64 + f_];
        if (row < 16) {
            int grp = row >> 2;
            float val = (zv - stats[grp][0]) * stats[grp][1];
            val = val * gq[row * 64 + f_] + betq[row * 64 + f_];
            int h = row >> 2, o = row & 3;
            Qo[(((size_t)(h * 2 + b)) * 2048 + t) * 256 + o * 64 + f_] = f2bf(val);
        } else if (row < 32) {
            int rr = row - 16, grp = 4 + (rr >> 2);
            float val = (zv - stats[grp][0]) * stats[grp][1];
            val = val * gk[rr * 64 + f_] + betk[rr * 64 + f_];
            int h = rr >> 2, o = rr & 3;
            Ko[(((size_t)(h * 2 + b)) * 2048 + t) * 256 + o * 64 + f_] = f2bf(val);
        } else {
            int rr = row - 32, grp = 8 + (rr >> 4);
            float val = (zv - stats[grp][0]) * stats[grp][1];
            val = val * gv[rr * 64 + f_] + betv[rr * 64 + f_];
            int h = rr >> 4, ov = rr & 15;
            Vo[(((size_t)(h * 2 + b)) * 2048 + t) * 1024 + ov * 64 + f_] = f2bf(val);
        }
    }
}

// ---------------------------------------------------------------------------
// Kernel 2: V row-major [hb][t][d] -> V^T [hb][d][pi(t)]: keys within each
// 64-aligned t-block stored in bit-permuted order pi so attn's PV B-frags
// are contiguous 16B loads. pi(k): out(5,4,3,2,1:0) = in(5,3,2,4,1:0).
// Inverse gather here: src = PINV(c) = c5*32 + c2*16 + c4*8 + c3*4 + c1:0.
// ---------------------------------------------------------------------------
__global__ __launch_bounds__(256) void vtrans_kernel(
    const short* __restrict__ Vrm, short* __restrict__ Vt)
{
    const int t0 = blockIdx.x * 64;
    const int d0 = blockIdx.y * 64;
    const int hb = blockIdx.z;
    const int tid = threadIdx.x;
    __shared__ __align__(16) short tile[64 * 72];

#pragma unroll
    for (int k = 0; k < 2; ++k) {
        int q = tid + 256 * k;
        int row = q >> 3, slot = q & 7;
        s16x8 v = *(const s16x8*)(Vrm + ((size_t)hb * 2048 + t0 + row) * 1024 + d0 + slot * 8);
        *(s16x8*)&tile[row * 72 + slot * 8] = v;
    }
    __syncthreads();
#pragma unroll
    for (int k = 0; k < 2; ++k) {
        int q = tid + 256 * k;
        int drow = q >> 3, tslot = q & 7;
        s16x8 v;
#pragma unroll
        for (int i = 0; i < 8; ++i) {
            int src = ((tslot >> 2) & 1) * 32 + ((i >> 2) & 1) * 16
                    + ((tslot >> 1) & 1) * 8 + (tslot & 1) * 4 + (i & 3);
            v[i] = tile[src * 72 + drow];
        }
        *(s16x8*)(Vt + ((size_t)hb * 1024 + d0 + drow) * 2048 + t0 + tslot * 8) = v;
    }
}

// ---------------------------------------------------------------------------
// Kernel 3: flash attention, wave-autonomous. Grid (8 hb, 16 qt, 2 dh) = 256
// blocks (1/CU). 8 waves x 16 q-rows = 128 rows/block; d-half 512 per block.
// Swapped QK^T: mfma(A=K, B=Q) -> S^T; lane owns full P-row for q=lane&15
// (16 key-values across 4 tiles). Key relabeling pi makes P feed PV's
// A-operand with ZERO cross-lane movement; V stored pi-permuted (vtrans).
// Per tile: [V batch0 loads | K(t+1) DMA | QK^T 32 MFMA | 16-exp softmax
// (+2 shfl for l) | PV 64 MFMA, ring-2 V reg batches] -> ONE barrier.
// No P-LDS, no mid-tile sync: waves drift -> MFMA/VALU phases overlap.
// ---------------------------------------------------------------------------
__global__ __launch_bounds__(512, 2) void attn_kernel(
    const short* __restrict__ Qg, const short* __restrict__ Kg,
    const short* __restrict__ Vt, short* __restrict__ Ob)
{
    const int hb = blockIdx.x;
    const int qt = blockIdx.y;     // 0..15
    const int dh = blockIdx.z;     // 0..1
    const int t0 = qt * 128;
    const int tid = threadIdx.x;
    const int lane = tid & 63;
    const int wq = tid >> 6;       // wave owns q-rows [t0 + wq*16, +16)
    const int g = lane >> 4, c16 = lane & 15;

    __shared__ __align__(16) short k_lds[2][64 * 256];   // 64 KB dbuf

    const size_t kgbase = (size_t)hb * 2048 * 256;
    const size_t vbase = (size_t)hb * 1024 + dh * 512;   // V^T row base (d)
    const int swz = c16 & 7;

    // Q B-fragments, persistent across all tiles (col=q=c16, k=kf*32+g*8+e)
    const size_t qrow = (size_t)hb * 2048 + t0 + wq * 16 + c16;
    s16x8 qf[8];
#pragma unroll
    for (int kf = 0; kf < 8; ++kf)
        qf[kf] = *(const s16x8*)(Qg + qrow * 256 + kf * 32 + g * 8);

    f32x4 oacc[32];                // [dtile 0..31]: O[q=g*4+r][d=dtile*16+c16]
#pragma unroll
    for (int i = 0; i < 32; ++i)
#pragma unroll
        for (int r = 0; r < 4; ++r) oacc[i][r] = 0.f;

    float l_r = 0.f;               // softmax denom for q = c16

    // DMA-stage K tile kt into k_lds[buf]: linear dest, inverse-swz source
#define STAGE_K(buf, kt) do {                                                  \
    _Pragma("unroll")                                                          \
    for (int j_ = 0; j_ < 4; ++j_) {                                           \
        int c_ = (wq * 4 + j_) * 64 + lane;                                    \
        int row_ = c_ >> 5, sp_ = c_ & 31;                                     \
        int slot_ = sp_ ^ (row_ & 7);                                          \
        gload16(Kg + kgbase + (size_t)((kt) * 64 + row_) * 256 + slot_ * 8,    \
                &k_lds[buf][(wq * 4 + j_) * 512]);                             \
    }                                                                          \
} while (0)

    // prologue: stage K tile 0
    STAGE_K(0, 0);
    __syncthreads();

    for (int t = 0; t < 32; ++t) {
        const int kt0 = t * 64;

        // V batch 0 (dtiles 0..3): 16B loads, contiguous thanks to pi-layout
        s16x8 vr[2][4][2];
#pragma unroll
        for (int d4 = 0; d4 < 4; ++d4)
#pragma unroll
            for (int s = 0; s < 2; ++s)
                vr[0][d4][s] = *(const s16x8*)(Vt + (vbase + d4 * 16 + c16) * 2048
                                               + kt0 + s * 32 + g * 8);

        // issue next K tile DMA (lands by the end-of-tile barrier)
        if (t < 31) STAGE_K((t + 1) & 1, t + 1);

        // QK^T swapped: sf[kt] = S^T[key = kt*16 + g*4 + r][q = c16]
        f32x4 sf[4];
#pragma unroll
        for (int kt = 0; kt < 4; ++kt)
#pragma unroll
            for (int r = 0; r < 4; ++r) sf[kt][r] = 0.f;
        __builtin_amdgcn_s_setprio(1);
#pragma unroll
        for (int kf = 0; kf < 8; ++kf) {
#pragma unroll
            for (int kt = 0; kt < 4; ++kt) {
                s16x8 kb = *(const s16x8*)&k_lds[t & 1]
                    [(kt * 16 + c16) * 256 + (((kf * 4 + g) ^ swz) * 8)];
                sf[kt] = __builtin_amdgcn_mfma_f32_16x16x32_bf16(kb, qf[kf], sf[kt], 0, 0, 0);
            }
        }
        __builtin_amdgcn_s_setprio(0);

        // softmax (no max: Q,K LayerNorm'd): 16 exp + row-sum via 2 shfl
        float rs = 0.f;
#pragma unroll
        for (int kt = 0; kt < 4; ++kt)
#pragma unroll
            for (int r = 0; r < 4; ++r) {
                float p = __expf(sf[kt][r] * 0.0625f);
                sf[kt][r] = p;
                rs += p;
            }
        rs += __shfl_xor(rs, 16);
        rs += __shfl_xor(rs, 32);
        l_r += rs;

        // pack P -> A-fragments (zero cross-lane: pi absorbs the layout)
        s16x8 pa0, pa1;
#pragma unroll
        for (int e = 0; e < 8; ++e) {
            pa0[e] = f2bf(sf[(e >> 2)][e & 3]);       // k'-step 0: tiles 0,1
            pa1[e] = f2bf(sf[2 + (e >> 2)][e & 3]);   // k'-step 1: tiles 2,3
        }

        // V batch 1 (dtiles 4..7)
#pragma unroll
        for (int d4 = 0; d4 < 4; ++d4)
#pragma unroll
            for (int s = 0; s < 2; ++s)
                vr[1][d4][s] = *(const s16x8*)(Vt + (vbase + (4 + d4) * 16 + c16) * 2048
                                               + kt0 + s * 32 + g * 8);

        // PV: 8 batches x 4 dtiles x 2 k'-steps = 64 MFMA, ring-2 V regs
#pragma unroll
        for (int bat = 0; bat < 8; ++bat) {
            __builtin_amdgcn_s_setprio(1);
#pragma unroll
            for (int d4 = 0; d4 < 4; ++d4) {
                oacc[bat * 4 + d4] = __builtin_amdgcn_mfma_f32_16x16x32_bf16(
                    pa0, vr[bat & 1][d4][0], oacc[bat * 4 + d4], 0, 0, 0);
                oacc[bat * 4 + d4] = __builtin_amdgcn_mfma_f32_16x16x32_bf16(
                    pa1, vr[bat & 1][d4][1], oacc[bat * 4 + d4], 0, 0, 0);
            }
            __builtin_amdgcn_s_setprio(0);
            if (bat < 6) {
#pragma unroll
                for (int d4 = 0; d4 < 4; ++d4)
#pragma unroll
                    for (int s = 0; s < 2; ++s)
                        vr[bat & 1][d4][s] = *(const s16x8*)(Vt
                            + (vbase + ((bat + 2) * 4 + d4) * 16 + c16) * 2048
                            + kt0 + s * 32 + g * 8);
            }
        }

        // one barrier per tile: K(t+1) DMA drained; k_lds[t&1] reads done
        if (t < 31) __syncthreads();
    }

#undef STAGE_K

    // epilogue: per-lane needs l for q = g*4 + r (lives in lane g*4+r)
    float li[4];
#pragma unroll
    for (int r = 0; r < 4; ++r)
        li[r] = 1.f / __shfl(l_r, g * 4 + r);

    const int h = hb >> 1, b = hb & 1;
#pragma unroll
    for (int dt = 0; dt < 32; ++dt) {
        int vcol = dh * 512 + dt * 16 + c16;
        int cout = h * 16 + (vcol >> 6), ff = vcol & 63;
#pragma unroll
        for (int r = 0; r < 4; ++r) {
            int trow = t0 + wq * 16 + g * 4 + r;
            Ob[(((size_t)b * 64 + cout) * 2048 + trow) * 64 + ff] =
                f2bf(oacc[dt][r] * li[r]);
        }
    }
}

// ---------------------------------------------------------------------------
// Kernel 4: output projection via MFMA + PReLU + LN(C,F) + residual
// ---------------------------------------------------------------------------
__global__ __launch_bounds__(256) void oproj_kernel(
    const short* __restrict__ Ob, const float* __restrict__ x,
    const short* __restrict__ Wpbf,
    const float* __restrict__ bp, const float* __restrict__ ap,
    const float* __restrict__ gp, const float* __restrict__ betp,
    float* __restrict__ out)
{
    const int t = blockIdx.x;
    const int b = blockIdx.y;
    const int tid = threadIdx.x;
    const int wid = tid >> 6, lane = tid & 63;
    const int g = lane >> 4, c16 = lane & 15;
    const int f_ = tid & 63, cg = tid >> 6;

    __shared__ __align__(16) short wp[64 * 64];
    __shared__ __align__(16) short os[64 * 64];
    __shared__ float zs[64 * 64];
    __shared__ float red[4][2];

#pragma unroll
    for (int j = 0; j < 2; ++j) {
        int i8 = tid + 256 * j;
        int row = i8 >> 3, cb = i8 & 7;
        s16x8 v = *(const s16x8*)(Wpbf + i8 * 8);
        *(s16x8*)&wp[row * 64 + ((cb ^ (row & 7)) * 8)] = v;
    }
#pragma unroll
    for (int it = 0; it < 2; ++it) {
        int cb = cg + 4 * it, c0 = cb * 8;
        s16x8 v;
#pragma unroll
        for (int i = 0; i < 8; ++i)
            v[i] = Ob[(((size_t)b * 64 + c0 + i) * 2048 + t) * 64 + f_];
        *(s16x8*)&os[f_ * 64 + ((cb ^ (f_ & 7)) * 8)] = v;
    }
    __syncthreads();

    const int f0 = wid * 16;
    s16x8 bfr[2];
#pragma unroll
    for (int kk = 0; kk < 2; ++kk)
        bfr[kk] = *(const s16x8*)&os[(f0 + c16) * 64 + (((kk * 4 + g) ^ (c16 & 7)) * 8)];

    const float ap0 = ap[0];
    f32x4 acc[4];
#pragma unroll
    for (int rt = 0; rt < 4; ++rt) {
#pragma unroll
        for (int r = 0; r < 4; ++r) acc[rt][r] = 0.f;
#pragma unroll
        for (int kk = 0; kk < 2; ++kk) {
            s16x8 a = *(const s16x8*)&wp[(rt * 16 + c16) * 64 + (((kk * 4 + g) ^ (c16 & 7)) * 8)];
            acc[rt] = __builtin_amdgcn_mfma_f32_16x16x32_bf16(a, bfr[kk], acc[rt], 0, 0, 0);
        }
    }

#pragma unroll
    for (int rt = 0; rt < 4; ++rt)
#pragma unroll
        for (int r = 0; r < 4; ++r) {
            int row = rt * 16 + g * 4 + r;
            float z = acc[rt][r] + bp[row];
            z = z >= 0.f ? z : ap0 * z;
            zs[row * 64 + f0 + c16] = z;
        }
    __syncthreads();

    float s = 0.f, ss = 0.f;
#pragma unroll
    for (int j = 0; j < 16; ++j) {
        float v = zs[(cg + 4 * j) * 64 + f_];
        s += v; ss += v * v;
    }
#pragma unroll
    for (int msk = 32; msk >= 1; msk >>= 1) {
        s  += __shfl_xor(s, msk);
        ss += __shfl_xor(ss, msk);
    }
    if (lane == 0) { red[wid][0] = s; red[wid][1] = ss; }
    __syncthreads();
    float ts  = red[0][0] + red[1][0] + red[2][0] + red[3][0];
    float tss = red[0][1] + red[1][1] + red[2][1] + red[3][1];
    float mean = ts * (1.f / 4096.f);
    float rstd = rsqrtf(tss * (1.f / 4096.f) - mean * mean + EPS_);

#pragma unroll
    for (int j = 0; j < 16; ++j) {
        int row = cg + 4 * j;
        size_t idx = (((size_t)b * 64 + row) * 2048 + t) * 64 + f_;
        out[idx] = (zs[row * 64 + f_] - mean) * rstd * gp[row * 64 + f_]
                 + betp[row * 64 + f_] + x[idx];
    }
}

// ---------------------------------------------------------------------------
extern "C" void kernel_launch(void* const* d_in, const int* in_sizes, int n_in,
                              void* d_out, int out_size, void* d_ws, size_t ws_size,
                              hipStream_t stream)
{
    const float* x    = (const float*)d_in[0];
    const float* Wq   = (const float*)d_in[1];
    const float* bq   = (const float*)d_in[2];
    const float* aq   = (const float*)d_in[3];
    const float* gq   = (const float*)d_in[4];
    const float* betq = (const float*)d_in[5];
    const float* Wk   = (const float*)d_in[6];
    const float* bk   = (const float*)d_in[7];
    const float* ak   = (const float*)d_in[8];
    const float* gk   = (const float*)d_in[9];
    const float* betk = (const float*)d_in[10];
    const float* Wv   = (const float*)d_in[11];
    const float* bv   = (const float*)d_in[12];
    const float* av   = (const float*)d_in[13];
    const float* gv   = (const float*)d_in[14];
    const float* betv = (const float*)d_in[15];
    const float* Wp   = (const float*)d_in[16];
    const float* bp   = (const float*)d_in[17];
    const float* ap   = (const float*)d_in[18];
    const float* gp   = (const float*)d_in[19];
    const float* betp = (const float*)d_in[20];

    short* Qb   = (short*)d_ws;
    short* Kb   = Qb   + (size_t)8 * 2048 * 256;
    short* Vrm  = Kb   + (size_t)8 * 2048 * 256;
    short* Vt   = Vrm  + (size_t)8 * 2048 * 1024;
    short* Obuf = Vt   + (size_t)8 * 2048 * 1024;
    short* Wbf  = Obuf + (size_t)8 * 2048 * 1024;
    short* Wpbf = Wbf  + 96 * 64;

    prep_kernel<<<40, 256, 0, stream>>>(Wq, Wk, Wv, Wp, Wbf, Wpbf);
    qkv_kernel<<<dim3(2048, 2), 256, 0, stream>>>(x, Wbf,
        bq, aq, gq, betq, bk, ak, gk, betk, bv, av, gv, betv, Qb, Kb, Vrm);
    vtrans_kernel<<<dim3(32, 16, 8), 256, 0, stream>>>(Vrm, Vt);
    attn_kernel<<<dim3(8, 16, 2), 512, 0, stream>>>(Qb, Kb, Vt, Obuf);
    oproj_kernel<<<dim3(2048, 2), 256, 0, stream>>>(Obuf, x, Wpbf,
        bp, ap, gp, betp, (float*)d_out);
}

// Round 9
// 490.776 us; speedup vs baseline: 1.3486x; 1.3486x over previous
//
#include <hip/hip_runtime.h>

#define EPS_ 1e-5f

typedef float f32x4 __attribute__((ext_vector_type(4)));
typedef short s16x8 __attribute__((ext_vector_type(8)));

static __device__ __forceinline__ short f2bf(float f) {
    unsigned u = __float_as_uint(f);
    unsigned r = (u + 0x7FFFu + ((u >> 16) & 1u)) >> 16;
    return (short)r;
}
static __device__ __forceinline__ float bf2f(short s) {
    return __uint_as_float(((unsigned)(unsigned short)s) << 16);
}

// async global->LDS, 16B per lane, wave-uniform LDS base
static __device__ __forceinline__ void gload16(const short* g, short* l) {
    __builtin_amdgcn_global_load_lds(
        (const __attribute__((address_space(1))) unsigned int*)g,
        (__attribute__((address_space(3))) unsigned int*)l, 16, 0, 0);
}

// ---------------------------------------------------------------------------
// Kernel 0: convert weight stacks to bf16 once.
// ---------------------------------------------------------------------------
__global__ __launch_bounds__(256) void prep_kernel(
    const float* __restrict__ Wq, const float* __restrict__ Wk,
    const float* __restrict__ Wv, const float* __restrict__ Wp,
    short* __restrict__ Wbf, short* __restrict__ Wpbf)
{
    int i = blockIdx.x * 256 + threadIdx.x;
    if (i < 6144) {
        float v = (i < 1024) ? Wq[i] : (i < 2048 ? Wk[i - 1024] : Wv[i - 2048]);
        Wbf[i] = f2bf(v);
    } else if (i < 6144 + 4096) {
        Wpbf[i - 6144] = f2bf(Wp[i - 6144]);
    }
}

// ---------------------------------------------------------------------------
// Kernel 1: QKV projection via MFMA + PReLU + LN(chan,freq), write bf16.
// ---------------------------------------------------------------------------
__global__ __launch_bounds__(256) void qkv_kernel(
    const float* __restrict__ x, const short* __restrict__ Wbf,
    const float* __restrict__ bq, const float* __restrict__ aq,
    const float* __restrict__ gq, const float* __restrict__ betq,
    const float* __restrict__ bk, const float* __restrict__ ak,
    const float* __restrict__ gk, const float* __restrict__ betk,
    const float* __restrict__ bv, const float* __restrict__ av,
    const float* __restrict__ gv, const float* __restrict__ betv,
    short* __restrict__ Qo, short* __restrict__ Ko, short* __restrict__ Vo)
{
    const int t = blockIdx.x;
    const int b = blockIdx.y;
    const int tid = threadIdx.x;
    const int wid = tid >> 6, lane = tid & 63;
    const int g = lane >> 4, c16 = lane & 15;
    const int f_ = tid & 63, cg = tid >> 6;

    __shared__ __align__(16) short wlds[96 * 64];
    __shared__ __align__(16) short xs[64 * 64];
    __shared__ float zs[96 * 64];
    __shared__ float stats[12][2];
    __shared__ float bias_l[96], alpha_l[96];

#pragma unroll
    for (int j = 0; j < 3; ++j) {
        int i8 = tid + 256 * j;
        int row = i8 >> 3, cb = i8 & 7;
        s16x8 v = *(const s16x8*)(Wbf + i8 * 8);
        *(s16x8*)&wlds[row * 64 + ((cb ^ (row & 7)) * 8)] = v;
    }
    if (tid < 96) {
        int row = tid; float bias, al;
        if (row < 16)      { bias = bq[row];      al = aq[row >> 2]; }
        else if (row < 32) { bias = bk[row - 16]; al = ak[(row - 16) >> 2]; }
        else               { bias = bv[row - 32]; al = av[(row - 32) >> 4]; }
        bias_l[row] = bias; alpha_l[row] = al;
    }
#pragma unroll
    for (int it = 0; it < 2; ++it) {
        int cb = cg + 4 * it, c0 = cb * 8;
        s16x8 v;
#pragma unroll
        for (int i = 0; i < 8; ++i)
            v[i] = f2bf(x[(((size_t)b * 64 + c0 + i) * 2048 + t) * 64 + f_]);
        *(s16x8*)&xs[f_ * 64 + ((cb ^ (f_ & 7)) * 8)] = v;
    }
    __syncthreads();

    const int f0 = wid * 16;
    s16x8 bfr[2];
#pragma unroll
    for (int kk = 0; kk < 2; ++kk)
        bfr[kk] = *(const s16x8*)&xs[(f0 + c16) * 64 + (((kk * 4 + g) ^ (c16 & 7)) * 8)];

    f32x4 acc[6];
#pragma unroll
    for (int rt = 0; rt < 6; ++rt) {
#pragma unroll
        for (int r = 0; r < 4; ++r) acc[rt][r] = 0.f;
#pragma unroll
        for (int kk = 0; kk < 2; ++kk) {
            s16x8 a = *(const s16x8*)&wlds[(rt * 16 + c16) * 64 + (((kk * 4 + g) ^ (c16 & 7)) * 8)];
            acc[rt] = __builtin_amdgcn_mfma_f32_16x16x32_bf16(a, bfr[kk], acc[rt], 0, 0, 0);
        }
    }

#pragma unroll
    for (int rt = 0; rt < 6; ++rt)
#pragma unroll
        for (int r = 0; r < 4; ++r) {
            int row = rt * 16 + g * 4 + r;
            float z = acc[rt][r] + bias_l[row];
            z = z >= 0.f ? z : alpha_l[row] * z;
            zs[row * 64 + f0 + c16] = z;
        }
    __syncthreads();

#pragma unroll
    for (int gi = 0; gi < 3; ++gi) {
        int grp = wid * 3 + gi;
        int base_row, n;
        if (grp < 4)      { base_row = grp * 4;             n = 256; }
        else if (grp < 8) { base_row = 16 + (grp - 4) * 4;  n = 256; }
        else              { base_row = 32 + (grp - 8) * 16; n = 1024; }
        int cnt = n >> 6;
        float s = 0.f, ss = 0.f;
        for (int i = 0; i < cnt; ++i) {
            float v = zs[(base_row + i) * 64 + lane];
            s += v; ss += v * v;
        }
#pragma unroll
        for (int msk = 32; msk >= 1; msk >>= 1) {
            s  += __shfl_xor(s, msk);
            ss += __shfl_xor(ss, msk);
        }
        if (lane == 0) {
            float mean = s / n;
            float var = ss / n - mean * mean;
            stats[grp][0] = mean;
            stats[grp][1] = rsqrtf(var + EPS_);
        }
    }
    __syncthreads();

#pragma unroll
    for (int j = 0; j < 24; ++j) {
        int row = cg + 4 * j;
        float zv = zs[row * 64 + f_];
        if (row < 16) {
            int grp = row >> 2;
            float val = (zv - stats[grp][0]) * stats[grp][1];
            val = val * gq[row * 64 + f_] + betq[row * 64 + f_];
            int h = row >> 2, o = row & 3;
            Qo[(((size_t)(h * 2 + b)) * 2048 + t) * 256 + o * 64 + f_] = f2bf(val);
        } else if (row < 32) {
            int rr = row - 16, grp = 4 + (rr >> 2);
            float val = (zv - stats[grp][0]) * stats[grp][1];
            val = val * gk[rr * 64 + f_] + betk[rr * 64 + f_];
            int h = rr >> 2, o = rr & 3;
            Ko[(((size_t)(h * 2 + b)) * 2048 + t) * 256 + o * 64 + f_] = f2bf(val);
        } else {
            int rr = row - 32, grp = 8 + (rr >> 4);
            float val = (zv - stats[grp][0]) * stats[grp][1];
            val = val * gv[rr * 64 + f_] + betv[rr * 64 + f_];
            int h = rr >> 4, ov = rr & 15;
            Vo[(((size_t)(h * 2 + b)) * 2048 + t) * 1024 + ov * 64 + f_] = f2bf(val);
        }
    }
}

// ---------------------------------------------------------------------------
// Kernel 2: V row-major [hb][t][d] -> V^T [hb][d][t]  (plain transpose)
// ---------------------------------------------------------------------------
__global__ __launch_bounds__(256) void vtrans_kernel(
    const short* __restrict__ Vrm, short* __restrict__ Vt)
{
    const int t0 = blockIdx.x * 64;
    const int d0 = blockIdx.y * 64;
    const int hb = blockIdx.z;
    const int tid = threadIdx.x;
    __shared__ __align__(16) short tile[64 * 72];

#pragma unroll
    for (int k = 0; k < 2; ++k) {
        int q = tid + 256 * k;
        int row = q >> 3, slot = q & 7;
        s16x8 v = *(const s16x8*)(Vrm + ((size_t)hb * 2048 + t0 + row) * 1024 + d0 + slot * 8);
        *(s16x8*)&tile[row * 72 + slot * 8] = v;
    }
    __syncthreads();
#pragma unroll
    for (int k = 0; k < 2; ++k) {
        int q = tid + 256 * k;
        int drow = q >> 3, tslot = q & 7;
        s16x8 v;
#pragma unroll
        for (int i = 0; i < 8; ++i)
            v[i] = tile[(tslot * 8 + i) * 72 + drow];
        *(s16x8*)(Vt + ((size_t)hb * 1024 + d0 + drow) * 2048 + t0 + tslot * 8) = v;
    }
}

// ---------------------------------------------------------------------------
// Kernel 3: flash attention, 4-wave blocks for 3-blocks/CU co-residency.
// Grid (8 hb, 32 qt, 4 dq) = 1024 blocks of 256 thr.
// QK^T: wave wid owns q-stripe [t0+wid*16,+16) x ALL 64 keys (32 MFMA, K=256)
//       -> wave-complete softmax l (no cross-wave combine per tile).
//       Duplicated across the 4 dq blocks (accepted cost).
// PV:   wave owns d-slice [dq*256 + wid*64, +64) for all 64 q (32 MFMA);
//       V direct global->reg ring-2; every V fragment loaded once per block.
// K: single 32KB LDS buffer via global_load_lds DMA (issue after bar1,
//    drained by bar2). p single 8.4KB. LDS ~41KB -> 3 blocks/CU.
// Regs: oacc 64 AGPR + ~100 VGPR <= 170 (launch_bounds(256,3)).
// ---------------------------------------------------------------------------
__global__ __launch_bounds__(256, 3) void attn_kernel(
    const short* __restrict__ Qg, const short* __restrict__ Kg,
    const short* __restrict__ Vt, short* __restrict__ Ob)
{
    const int hb = blockIdx.x;
    const int qt = blockIdx.y;     // 0..31
    const int dq = blockIdx.z;     // 0..3 (d-quarter)
    const int t0 = qt * 64;
    const int tid = threadIdx.x;
    const int lane = tid & 63;
    const int wid = tid >> 6;      // q-stripe (QK^T) / d-slice (PV)
    const int g = lane >> 4, c16 = lane & 15;

    __shared__ __align__(16) short k_lds[64 * 256];   // 32 KB single buffer
    __shared__ __align__(16) short p_lds[64 * 66];    // 8.4 KB
    __shared__ float l_sh[64];

    const size_t kgbase = (size_t)hb * 2048 * 256;
    const int dsl = dq * 256 + wid * 64;              // this wave's V d-slice
    const size_t vrow0 = (size_t)hb * 1024 + dsl + c16;

    // Q fragments for stripe wid, persistent (16 rows x 256 d)
    const size_t qbase = ((size_t)hb * 2048 + t0 + wid * 16 + c16) * 256;
    s16x8 qf[8];
#pragma unroll
    for (int kf = 0; kf < 8; ++kf)
        qf[kf] = *(const s16x8*)(Qg + qbase + kf * 32 + g * 8);

    f32x4 oacc[16];                // [dt 0..3][qs2 0..3]
#pragma unroll
    for (int i = 0; i < 16; ++i)
#pragma unroll
        for (int r = 0; r < 4; ++r) oacc[i][r] = 0.f;

    float l_r[4] = {0.f, 0.f, 0.f, 0.f};

    // DMA-stage K tile kt into k_lds: linear dest, inverse-swizzled source
#define STAGE_K(kt) do {                                                       \
    _Pragma("unroll")                                                          \
    for (int j_ = 0; j_ < 8; ++j_) {                                           \
        int c_ = (wid * 8 + j_) * 64 + lane;                                   \
        int row_ = c_ >> 5, sp_ = c_ & 31;                                     \
        int slot_ = sp_ ^ (row_ & 7);                                          \
        gload16(Kg + kgbase + (size_t)((kt) * 64 + row_) * 256 + slot_ * 8,    \
                &k_lds[(wid * 8 + j_) * 512]);                                 \
    }                                                                          \
} while (0)

    // prologue: stage K tile 0
    STAGE_K(0);
    __syncthreads();

    for (int t = 0; t < 32; ++t) {
        const int kt0 = t * 64;

        // QK^T: 16 q-rows x 64 keys, K=256 (32 MFMA)
        f32x4 sf[4];
#pragma unroll
        for (int nf = 0; nf < 4; ++nf)
#pragma unroll
            for (int r = 0; r < 4; ++r) sf[nf][r] = 0.f;
        __builtin_amdgcn_s_setprio(1);
#pragma unroll
        for (int kf = 0; kf < 8; ++kf) {
#pragma unroll
            for (int nf = 0; nf < 4; ++nf) {
                int krow = nf * 16 + c16;
                s16x8 kb = *(const s16x8*)&k_lds[krow * 256 + (((kf * 4 + g) ^ (krow & 7)) * 8)];
                sf[nf] = __builtin_amdgcn_mfma_f32_16x16x32_bf16(qf[kf], kb, sf[nf], 0, 0, 0);
            }
        }
        __builtin_amdgcn_s_setprio(0);

        // V prefetch for dt 0,1 (issued early; softmax + bar hide latency)
        s16x8 vf[2][2];
#pragma unroll
        for (int dt = 0; dt < 2; ++dt)
#pragma unroll
            for (int ks = 0; ks < 2; ++ks)
                vf[dt][ks] = *(const s16x8*)(Vt + (vrow0 + dt * 16) * 2048 + kt0 + (ks * 4 + g) * 8);

        // softmax (no max: Q,K LayerNorm'd): 16 exp + row-sums over 64 keys
        float rs[4] = {0.f, 0.f, 0.f, 0.f};
#pragma unroll
        for (int nf = 0; nf < 4; ++nf)
#pragma unroll
            for (int r = 0; r < 4; ++r) {
                float p = __expf(sf[nf][r] * 0.0625f);
                sf[nf][r] = p;
                rs[r] += p;
            }
#pragma unroll
        for (int msk = 1; msk <= 8; msk <<= 1)
#pragma unroll
            for (int r = 0; r < 4; ++r) rs[r] += __shfl_xor(rs[r], msk);
#pragma unroll
        for (int r = 0; r < 4; ++r) l_r[r] += rs[r];

        // write P stripe (16 q x 64 k, bf16)
#pragma unroll
        for (int nf = 0; nf < 4; ++nf)
#pragma unroll
            for (int r = 0; r < 4; ++r)
                p_lds[(wid * 16 + g * 4 + r) * 66 + nf * 16 + c16] = f2bf(sf[nf][r]);

        __syncthreads();   // bar1: P visible; k_lds reads done

        // DMA next K tile (drained at bar2; PV covers the latency)
        if (t < 31) STAGE_K(t + 1);

        // P A-fragments for all 4 q-stripes
        s16x8 pa[4][2];
#pragma unroll
        for (int qs2 = 0; qs2 < 4; ++qs2)
#pragma unroll
            for (int ks = 0; ks < 2; ++ks)
                pa[qs2][ks] = *(const s16x8*)&p_lds[(qs2 * 16 + c16) * 66 + ks * 32 + g * 8];

        // PV: 4 d-tiles x 4 q-stripes x 2 ks (32 MFMA), ring-2 V regs
#pragma unroll
        for (int dt = 0; dt < 4; ++dt) {
            __builtin_amdgcn_s_setprio(1);
#pragma unroll
            for (int qs2 = 0; qs2 < 4; ++qs2)
#pragma unroll
                for (int ks = 0; ks < 2; ++ks)
                    oacc[dt * 4 + qs2] = __builtin_amdgcn_mfma_f32_16x16x32_bf16(
                        pa[qs2][ks], vf[dt & 1][ks], oacc[dt * 4 + qs2], 0, 0, 0);
            __builtin_amdgcn_s_setprio(0);
            if (dt < 2) {
#pragma unroll
                for (int ks = 0; ks < 2; ++ks)
                    vf[dt & 1][ks] = *(const s16x8*)(Vt + (vrow0 + (dt + 2) * 16) * 2048 + kt0 + (ks * 4 + g) * 8);
            }
        }

        __syncthreads();   // bar2: K(t+1) staged; p_lds reads done
    }

#undef STAGE_K

    // share softmax denominators across waves (each wave owns its q-stripe)
    if (c16 == 0) {
#pragma unroll
        for (int r = 0; r < 4; ++r)
            l_sh[wid * 16 + g * 4 + r] = l_r[r];
    }
    __syncthreads();

    float li[16];
#pragma unroll
    for (int qs2 = 0; qs2 < 4; ++qs2)
#pragma unroll
        for (int r = 0; r < 4; ++r)
            li[qs2 * 4 + r] = 1.f / l_sh[qs2 * 16 + g * 4 + r];

    // epilogue: O /= l, write bf16 in [b][h*16+ov][t][f] layout
    const int h = hb >> 1, b = hb & 1;
#pragma unroll
    for (int dt = 0; dt < 4; ++dt) {
        int vcol = dsl + dt * 16 + c16;
        int cout = h * 16 + (vcol >> 6), ff = vcol & 63;
#pragma unroll
        for (int qs2 = 0; qs2 < 4; ++qs2)
#pragma unroll
            for (int r = 0; r < 4; ++r) {
                int trow = t0 + qs2 * 16 + g * 4 + r;
                Ob[(((size_t)b * 64 + cout) * 2048 + trow) * 64 + ff] =
                    f2bf(oacc[dt * 4 + qs2][r] * li[qs2 * 4 + r]);
            }
    }
}

// ---------------------------------------------------------------------------
// Kernel 4: output projection via MFMA + PReLU + LN(C,F) + residual
// ---------------------------------------------------------------------------
__global__ __launch_bounds__(256) void oproj_kernel(
    const short* __restrict__ Ob, const float* __restrict__ x,
    const short* __restrict__ Wpbf,
    const float* __restrict__ bp, const float* __restrict__ ap,
    const float* __restrict__ gp, const float* __restrict__ betp,
    float* __restrict__ out)
{
    const int t = blockIdx.x;
    const int b = blockIdx.y;
    const int tid = threadIdx.x;
    const int wid = tid >> 6, lane = tid & 63;
    const int g = lane >> 4, c16 = lane & 15;
    const int f_ = tid & 63, cg = tid >> 6;

    __shared__ __align__(16) short wp[64 * 64];
    __shared__ __align__(16) short os[64 * 64];
    __shared__ float zs[64 * 64];
    __shared__ float red[4][2];

#pragma unroll
    for (int j = 0; j < 2; ++j) {
        int i8 = tid + 256 * j;
        int row = i8 >> 3, cb = i8 & 7;
        s16x8 v = *(const s16x8*)(Wpbf + i8 * 8);
        *(s16x8*)&wp[row * 64 + ((cb ^ (row & 7)) * 8)] = v;
    }
#pragma unroll
    for (int it = 0; it < 2; ++it) {
        int cb = cg + 4 * it, c0 = cb * 8;
        s16x8 v;
#pragma unroll
        for (int i = 0; i < 8; ++i)
            v[i] = Ob[(((size_t)b * 64 + c0 + i) * 2048 + t) * 64 + f_];
        *(s16x8*)&os[f_ * 64 + ((cb ^ (f_ & 7)) * 8)] = v;
    }
    __syncthreads();

    const int f0 = wid * 16;
    s16x8 bfr[2];
#pragma unroll
    for (int kk = 0; kk < 2; ++kk)
        bfr[kk] = *(const s16x8*)&os[(f0 + c16) * 64 + (((kk * 4 + g) ^ (c16 & 7)) * 8)];

    const float ap0 = ap[0];
    f32x4 acc[4];
#pragma unroll
    for (int rt = 0; rt < 4; ++rt) {
#pragma unroll
        for (int r = 0; r < 4; ++r) acc[rt][r] = 0.f;
#pragma unroll
        for (int kk = 0; kk < 2; ++kk) {
            s16x8 a = *(const s16x8*)&wp[(rt * 16 + c16) * 64 + (((kk * 4 + g) ^ (c16 & 7)) * 8)];
            acc[rt] = __builtin_amdgcn_mfma_f32_16x16x32_bf16(a, bfr[kk], acc[rt], 0, 0, 0);
        }
    }

#pragma unroll
    for (int rt = 0; rt < 4; ++rt)
#pragma unroll
        for (int r = 0; r < 4; ++r) {
            int row = rt * 16 + g * 4 + r;
            float z = acc[rt][r] + bp[row];
            z = z >= 0.f ? z : ap0 * z;
            zs[row * 64 + f0 + c16] = z;
        }
    __syncthreads();

    float s = 0.f, ss = 0.f;
#pragma unroll
    for (int j = 0; j < 16; ++j) {
        float v = zs[(cg + 4 * j) * 64 + f_];
        s += v; ss += v * v;
    }
#pragma unroll
    for (int msk = 32; msk >= 1; msk >>= 1) {
        s  += __shfl_xor(s, msk);
        ss += __shfl_xor(ss, msk);
    }
    if (lane == 0) { red[wid][0] = s; red[wid][1] = ss; }
    __syncthreads();
    float ts  = red[0][0] + red[1][0] + red[2][0] + red[3][0];
    float tss = red[0][1] + red[1][1] + red[2][1] + red[3][1];
    float mean = ts * (1.f / 4096.f);
    float rstd = rsqrtf(tss * (1.f / 4096.f) - mean * mean + EPS_);

#pragma unroll
    for (int j = 0; j < 16; ++j) {
        int row = cg + 4 * j;
        size_t idx = (((size_t)b * 64 + row) * 2048 + t) * 64 + f_;
        out[idx] = (zs[row * 64 + f_] - mean) * rstd * gp[row * 64 + f_]
                 + betp[row * 64 + f_] + x[idx];
    }
}

// ---------------------------------------------------------------------------
extern "C" void kernel_launch(void* const* d_in, const int* in_sizes, int n_in,
                              void* d_out, int out_size, void* d_ws, size_t ws_size,
                              hipStream_t stream)
{
    const float* x    = (const float*)d_in[0];
    const float* Wq   = (const float*)d_in[1];
    const float* bq   = (const float*)d_in[2];
    const float* aq   = (const float*)d_in[3];
    const float* gq   = (const float*)d_in[4];
    const float* betq = (const float*)d_in[5];
    const float* Wk   = (const float*)d_in[6];
    const float* bk   = (const float*)d_in[7];
    const float* ak   = (const float*)d_in[8];
    const float* gk   = (const float*)d_in[9];
    const float* betk = (const float*)d_in[10];
    const float* Wv   = (const float*)d_in[11];
    const float* bv   = (const float*)d_in[12];
    const float* av   = (const float*)d_in[13];
    const float* gv   = (const float*)d_in[14];
    const float* betv = (const float*)d_in[15];
    const float* Wp   = (const float*)d_in[16];
    const float* bp   = (const float*)d_in[17];
    const float* ap   = (const float*)d_in[18];
    const float* gp   = (const float*)d_in[19];
    const float* betp = (const float*)d_in[20];

    short* Qb   = (short*)d_ws;
    short* Kb   = Qb   + (size_t)8 * 2048 * 256;
    short* Vrm  = Kb   + (size_t)8 * 2048 * 256;
    short* Vt   = Vrm  + (size_t)8 * 2048 * 1024;
    short* Obuf = Vt   + (size_t)8 * 2048 * 1024;
    short* Wbf  = Obuf + (size_t)8 * 2048 * 1024;
    short* Wpbf = Wbf  + 96 * 64;

    prep_kernel<<<40, 256, 0, stream>>>(Wq, Wk, Wv, Wp, Wbf, Wpbf);
    qkv_kernel<<<dim3(2048, 2), 256, 0, stream>>>(x, Wbf,
        bq, aq, gq, betq, bk, ak, gk, betk, bv, av, gv, betv, Qb, Kb, Vrm);
    vtrans_kernel<<<dim3(32, 16, 8), 256, 0, stream>>>(Vrm, Vt);
    attn_kernel<<<dim3(8, 32, 4), 256, 0, stream>>>(Qb, Kb, Vt, Obuf);
    oproj_kernel<<<dim3(2048, 2), 256, 0, stream>>>(Obuf, x, Wpbf,
        bp, ap, gp, betp, (float*)d_out);
}

// Round 10
// 310.075 us; speedup vs baseline: 2.1345x; 1.5828x over previous
//
#include <hip/hip_runtime.h>

#define EPS_ 1e-5f

typedef float f32x4 __attribute__((ext_vector_type(4)));
typedef short s16x8 __attribute__((ext_vector_type(8)));

static __device__ __forceinline__ short f2bf(float f) {
    unsigned u = __float_as_uint(f);
    unsigned r = (u + 0x7FFFu + ((u >> 16) & 1u)) >> 16;
    return (short)r;
}
static __device__ __forceinline__ float bf2f(short s) {
    return __uint_as_float(((unsigned)(unsigned short)s) << 16);
}

// async global->LDS, 16B per lane, wave-uniform LDS base
static __device__ __forceinline__ void gload16(const short* g, short* l) {
    __builtin_amdgcn_global_load_lds(
        (const __attribute__((address_space(1))) unsigned int*)g,
        (__attribute__((address_space(3))) unsigned int*)l, 16, 0, 0);
}

// ---------------------------------------------------------------------------
// Kernel 0: convert weight stacks to bf16 once.
// ---------------------------------------------------------------------------
__global__ __launch_bounds__(256) void prep_kernel(
    const float* __restrict__ Wq, const float* __restrict__ Wk,
    const float* __restrict__ Wv, const float* __restrict__ Wp,
    short* __restrict__ Wbf, short* __restrict__ Wpbf)
{
    int i = blockIdx.x * 256 + threadIdx.x;
    if (i < 6144) {
        float v = (i < 1024) ? Wq[i] : (i < 2048 ? Wk[i - 1024] : Wv[i - 2048]);
        Wbf[i] = f2bf(v);
    } else if (i < 6144 + 4096) {
        Wpbf[i - 6144] = f2bf(Wp[i - 6144]);
    }
}

// ---------------------------------------------------------------------------
// Kernel 1: QKV projection via MFMA + PReLU + LN(chan,freq), write bf16.
// ---------------------------------------------------------------------------
__global__ __launch_bounds__(256) void qkv_kernel(
    const float* __restrict__ x, const short* __restrict__ Wbf,
    const float* __restrict__ bq, const float* __restrict__ aq,
    const float* __restrict__ gq, const float* __restrict__ betq,
    const float* __restrict__ bk, const float* __restrict__ ak,
    const float* __restrict__ gk, const float* __restrict__ betk,
    const float* __restrict__ bv, const float* __restrict__ av,
    const float* __restrict__ gv, const float* __restrict__ betv,
    short* __restrict__ Qo, short* __restrict__ Ko, short* __restrict__ Vo)
{
    const int t = blockIdx.x;
    const int b = blockIdx.y;
    const int tid = threadIdx.x;
    const int wid = tid >> 6, lane = tid & 63;
    const int g = lane >> 4, c16 = lane & 15;
    const int f_ = tid & 63, cg = tid >> 6;

    __shared__ __align__(16) short wlds[96 * 64];
    __shared__ __align__(16) short xs[64 * 64];
    __shared__ float zs[96 * 64];
    __shared__ float stats[12][2];
    __shared__ float bias_l[96], alpha_l[96];

#pragma unroll
    for (int j = 0; j < 3; ++j) {
        int i8 = tid + 256 * j;
        int row = i8 >> 3, cb = i8 & 7;
        s16x8 v = *(const s16x8*)(Wbf + i8 * 8);
        *(s16x8*)&wlds[row * 64 + ((cb ^ (row & 7)) * 8)] = v;
    }
    if (tid < 96) {
        int row = tid; float bias, al;
        if (row < 16)      { bias = bq[row];      al = aq[row >> 2]; }
        else if (row < 32) { bias = bk[row - 16]; al = ak[(row - 16) >> 2]; }
        else               { bias = bv[row - 32]; al = av[(row - 32) >> 4]; }
        bias_l[row] = bias; alpha_l[row] = al;
    }
#pragma unroll
    for (int it = 0; it < 2; ++it) {
        int cb = cg + 4 * it, c0 = cb * 8;
        s16x8 v;
#pragma unroll
        for (int i = 0; i < 8; ++i)
            v[i] = f2bf(x[(((size_t)b * 64 + c0 + i) * 2048 + t) * 64 + f_]);
        *(s16x8*)&xs[f_ * 64 + ((cb ^ (f_ & 7)) * 8)] = v;
    }
    __syncthreads();

    const int f0 = wid * 16;
    s16x8 bfr[2];
#pragma unroll
    for (int kk = 0; kk < 2; ++kk)
        bfr[kk] = *(const s16x8*)&xs[(f0 + c16) * 64 + (((kk * 4 + g) ^ (c16 & 7)) * 8)];

    f32x4 acc[6];
#pragma unroll
    for (int rt = 0; rt < 6; ++rt) {
#pragma unroll
        for (int r = 0; r < 4; ++r) acc[rt][r] = 0.f;
#pragma unroll
        for (int kk = 0; kk < 2; ++kk) {
            s16x8 a = *(const s16x8*)&wlds[(rt * 16 + c16) * 64 + (((kk * 4 + g) ^ (c16 & 7)) * 8)];
            acc[rt] = __builtin_amdgcn_mfma_f32_16x16x32_bf16(a, bfr[kk], acc[rt], 0, 0, 0);
        }
    }

#pragma unroll
    for (int rt = 0; rt < 6; ++rt)
#pragma unroll
        for (int r = 0; r < 4; ++r) {
            int row = rt * 16 + g * 4 + r;
            float z = acc[rt][r] + bias_l[row];
            z = z >= 0.f ? z : alpha_l[row] * z;
            zs[row * 64 + f0 + c16] = z;
        }
    __syncthreads();

#pragma unroll
    for (int gi = 0; gi < 3; ++gi) {
        int grp = wid * 3 + gi;
        int base_row, n;
        if (grp < 4)      { base_row = grp * 4;             n = 256; }
        else if (grp < 8) { base_row = 16 + (grp - 4) * 4;  n = 256; }
        else              { base_row = 32 + (grp - 8) * 16; n = 1024; }
        int cnt = n >> 6;
        float s = 0.f, ss = 0.f;
        for (int i = 0; i < cnt; ++i) {
            float v = zs[(base_row + i) * 64 + lane];
            s += v; ss += v * v;
        }
#pragma unroll
        for (int msk = 32; msk >= 1; msk >>= 1) {
            s  += __shfl_xor(s, msk);
            ss += __shfl_xor(ss, msk);
        }
        if (lane == 0) {
            float mean = s / n;
            float var = ss / n - mean * mean;
            stats[grp][0] = mean;
            stats[grp][1] = rsqrtf(var + EPS_);
        }
    }
    __syncthreads();

#pragma unroll
    for (int j = 0; j < 24; ++j) {
        int row = cg + 4 * j;
        float zv = zs[row * 64 + f_];
        if (row < 16) {
            int grp = row >> 2;
            float val = (zv - stats[grp][0]) * stats[grp][1];
            val = val * gq[row * 64 + f_] + betq[row * 64 + f_];
            int h = row >> 2, o = row & 3;
            Qo[(((size_t)(h * 2 + b)) * 2048 + t) * 256 + o * 64 + f_] = f2bf(val);
        } else if (row < 32) {
            int rr = row - 16, grp = 4 + (rr >> 2);
            float val = (zv - stats[grp][0]) * stats[grp][1];
            val = val * gk[rr * 64 + f_] + betk[rr * 64 + f_];
            int h = rr >> 2, o = rr & 3;
            Ko[(((size_t)(h * 2 + b)) * 2048 + t) * 256 + o * 64 + f_] = f2bf(val);
        } else {
            int rr = row - 32, grp = 8 + (rr >> 4);
            float val = (zv - stats[grp][0]) * stats[grp][1];
            val = val * gv[rr * 64 + f_] + betv[rr * 64 + f_];
            int h = rr >> 4, ov = rr & 15;
            Vo[(((size_t)(h * 2 + b)) * 2048 + t) * 1024 + ov * 64 + f_] = f2bf(val);
        }
    }
}

// ---------------------------------------------------------------------------
// Kernel 2: V row-major [hb][t][d] -> V^T [hb][d][t]
// ---------------------------------------------------------------------------
__global__ __launch_bounds__(256) void vtrans_kernel(
    const short* __restrict__ Vrm, short* __restrict__ Vt)
{
    const int t0 = blockIdx.x * 64;
    const int d0 = blockIdx.y * 64;
    const int hb = blockIdx.z;
    const int tid = threadIdx.x;
    __shared__ __align__(16) short tile[64 * 72];

#pragma unroll
    for (int k = 0; k < 2; ++k) {
        int q = tid + 256 * k;
        int row = q >> 3, slot = q & 7;
        s16x8 v = *(const s16x8*)(Vrm + ((size_t)hb * 2048 + t0 + row) * 1024 + d0 + slot * 8);
        *(s16x8*)&tile[row * 72 + slot * 8] = v;
    }
    __syncthreads();
#pragma unroll
    for (int k = 0; k < 2; ++k) {
        int q = tid + 256 * k;
        int drow = q >> 3, tslot = q & 7;
        s16x8 v;
#pragma unroll
        for (int i = 0; i < 8; ++i)
            v[i] = tile[(tslot * 8 + i) * 72 + drow];
        *(s16x8*)(Vt + ((size_t)hb * 1024 + d0 + drow) * 2048 + t0 + tslot * 8) = v;
    }
}

// ---------------------------------------------------------------------------
// Kernel 3: flash attention, QBLK=128 (V reuse doubled), d-half split.
// Grid (8 hb, 16 qt, 2 dh) = 256 blocks (1/CU), 512 thr (8 waves).
// QK^T: wave wid owns q-stripe [t0+wid*16,+16) x ALL 64 keys (32 MFMA) ->
//       wave-complete softmax l. Duplicated x2 across dh (cheap).
// PV: wave owns d-slice [dh*512+wid*64,+64) for ALL 128 q (64 MFMA);
//     each block reads only its 512-d half of V: 64 KB per tile (was 128).
// Pipeline (1 barrier/tile): vf all-8 upfront | STAGE_K(t+2) DMA |
// QKT(t+1) -> p[(t+1)&1] | PV(t) from p[t&1] | barrier.
// ---------------------------------------------------------------------------
__global__ __launch_bounds__(512, 2) void attn_kernel(
    const short* __restrict__ Qg, const short* __restrict__ Kg,
    const short* __restrict__ Vt, short* __restrict__ Ob)
{
    const int hb = blockIdx.x;
    const int qt = blockIdx.y;     // 0..15
    const int dh = blockIdx.z;     // 0..1
    const int t0 = qt * 128;
    const int tid = threadIdx.x;
    const int lane = tid & 63;
    const int wid = tid >> 6;
    const int g = lane >> 4, c16 = lane & 15;

    __shared__ __align__(16) short k_lds[2][64 * 256];    // 64 KB dbuf
    __shared__ __align__(16) short p_lds[2][128 * 66];    // 33.8 KB dbuf
    __shared__ float l_sh[128];

    const size_t kgbase = (size_t)hb * 2048 * 256;
    const int dsl = dh * 512 + wid * 64;                  // this wave's V d-slice
    const size_t vrow0 = (size_t)hb * 1024 + dsl + c16;

    // Q fragments for stripe wid (16 rows x 256 d), persistent
    const size_t qbase = ((size_t)hb * 2048 + t0 + wid * 16 + c16) * 256;
    s16x8 qf[8];
#pragma unroll
    for (int kf = 0; kf < 8; ++kf)
        qf[kf] = *(const s16x8*)(Qg + qbase + kf * 32 + g * 8);

    f32x4 oacc[32];                // [qs2 0..7][dt 0..3]
#pragma unroll
    for (int i = 0; i < 32; ++i)
#pragma unroll
        for (int r = 0; r < 4; ++r) oacc[i][r] = 0.f;

    float l_r[4] = {0.f, 0.f, 0.f, 0.f};

    // DMA-stage K tile kt into k_lds[buf]: linear dest, inverse-swz source
#define STAGE_K(buf, kt) do {                                                  \
    _Pragma("unroll")                                                          \
    for (int j_ = 0; j_ < 4; ++j_) {                                           \
        int c_ = (wid * 4 + j_) * 64 + lane;                                   \
        int row_ = c_ >> 5, sp_ = c_ & 31;                                     \
        int slot_ = sp_ ^ (row_ & 7);                                          \
        gload16(Kg + kgbase + (size_t)((kt) * 64 + row_) * 256 + slot_ * 8,    \
                &k_lds[buf][(wid * 4 + j_) * 512]);                            \
    }                                                                          \
} while (0)

    // QK^T for tile nt: 16 q x 64 keys, K=256 (32 MFMA); exp; l; p[(nt)&1]
#define QKT_PHASE(nt) do {                                                     \
    f32x4 sf[4];                                                               \
    _Pragma("unroll")                                                          \
    for (int nf = 0; nf < 4; ++nf)                                             \
        _Pragma("unroll")                                                      \
        for (int r = 0; r < 4; ++r) sf[nf][r] = 0.f;                           \
    __builtin_amdgcn_s_setprio(1);                                             \
    _Pragma("unroll")                                                          \
    for (int kf = 0; kf < 8; ++kf) {                                           \
        _Pragma("unroll")                                                      \
        for (int nf = 0; nf < 4; ++nf) {                                       \
            int krow = nf * 16 + c16;                                          \
            s16x8 kb = *(const s16x8*)&k_lds[(nt) & 1]                         \
                [krow * 256 + (((kf * 4 + g) ^ (krow & 7)) * 8)];              \
            sf[nf] = __builtin_amdgcn_mfma_f32_16x16x32_bf16(qf[kf], kb, sf[nf], 0, 0, 0); \
        }                                                                      \
    }                                                                          \
    __builtin_amdgcn_s_setprio(0);                                             \
    float rs[4] = {0.f, 0.f, 0.f, 0.f};                                        \
    _Pragma("unroll")                                                          \
    for (int nf = 0; nf < 4; ++nf)                                             \
        _Pragma("unroll")                                                      \
        for (int r = 0; r < 4; ++r) {                                          \
            float p = __expf(sf[nf][r] * 0.0625f);                             \
            sf[nf][r] = p;                                                     \
            rs[r] += p;                                                        \
        }                                                                      \
    _Pragma("unroll")                                                          \
    for (int msk = 1; msk <= 8; msk <<= 1)                                     \
        _Pragma("unroll")                                                      \
        for (int r = 0; r < 4; ++r) rs[r] += __shfl_xor(rs[r], msk);           \
    _Pragma("unroll")                                                          \
    for (int r = 0; r < 4; ++r) l_r[r] += rs[r];                               \
    _Pragma("unroll")                                                          \
    for (int nf = 0; nf < 4; ++nf)                                             \
        _Pragma("unroll")                                                      \
        for (int r = 0; r < 4; ++r)                                            \
            p_lds[(nt) & 1][(wid * 16 + g * 4 + r) * 66 + nf * 16 + c16]       \
                = f2bf(sf[nf][r]);                                             \
} while (0)

    // prologue
    STAGE_K(0, 0);
    __syncthreads();
    STAGE_K(1, 1);          // async: drained by the barrier below
    QKT_PHASE(0);
    __syncthreads();

    for (int t = 0; t < 32; ++t) {
        const int kt0 = t * 64;

        // all 8 V fragments for PV(t) up-front (QKT(t+1) covers L2 latency)
        s16x8 vf[4][2];
#pragma unroll
        for (int dt = 0; dt < 4; ++dt)
#pragma unroll
            for (int ks = 0; ks < 2; ++ks)
                vf[dt][ks] = *(const s16x8*)(Vt + (vrow0 + dt * 16) * 2048 + kt0 + (ks * 4 + g) * 8);

        if (t < 30) STAGE_K(t & 1, t + 2);
        if (t < 31) QKT_PHASE(t + 1);

        // PV(t): 8 q-stripes x 4 d-tiles x 2 ks = 64 MFMA, in 2 halves
#pragma unroll
        for (int h2 = 0; h2 < 2; ++h2) {
            s16x8 pa[4][2];
#pragma unroll
            for (int qs = 0; qs < 4; ++qs)
#pragma unroll
                for (int ks = 0; ks < 2; ++ks)
                    pa[qs][ks] = *(const s16x8*)&p_lds[t & 1]
                        [((h2 * 4 + qs) * 16 + c16) * 66 + ks * 32 + g * 8];
            __builtin_amdgcn_s_setprio(1);
#pragma unroll
            for (int qs = 0; qs < 4; ++qs)
#pragma unroll
                for (int dt = 0; dt < 4; ++dt)
#pragma unroll
                    for (int ks = 0; ks < 2; ++ks)
                        oacc[(h2 * 4 + qs) * 4 + dt] = __builtin_amdgcn_mfma_f32_16x16x32_bf16(
                            pa[qs][ks], vf[dt][ks], oacc[(h2 * 4 + qs) * 4 + dt], 0, 0, 0);
            __builtin_amdgcn_s_setprio(0);
        }

        if (t < 31) __syncthreads();
    }

#undef STAGE_K
#undef QKT_PHASE

    // share softmax denominators (each wave owns its q-stripe)
    __syncthreads();
    if (c16 == 0) {
#pragma unroll
        for (int r = 0; r < 4; ++r)
            l_sh[wid * 16 + g * 4 + r] = l_r[r];
    }
    __syncthreads();

    // epilogue: O /= l, write bf16 in [b][h*16+ov][t][f] layout
    const int h = hb >> 1, b = hb & 1;
#pragma unroll
    for (int qs2 = 0; qs2 < 8; ++qs2) {
#pragma unroll
        for (int dt = 0; dt < 4; ++dt) {
            int vcol = dsl + dt * 16 + c16;
            int cout = h * 16 + (vcol >> 6), ff = vcol & 63;
#pragma unroll
            for (int r = 0; r < 4; ++r) {
                int trow = t0 + qs2 * 16 + g * 4 + r;
                float li = 1.f / l_sh[qs2 * 16 + g * 4 + r];
                Ob[(((size_t)b * 64 + cout) * 2048 + trow) * 64 + ff] =
                    f2bf(oacc[qs2 * 4 + dt][r] * li);
            }
        }
    }
}

// ---------------------------------------------------------------------------
// Kernel 4: output projection via MFMA + PReLU + LN(C,F) + residual
// ---------------------------------------------------------------------------
__global__ __launch_bounds__(256) void oproj_kernel(
    const short* __restrict__ Ob, const float* __restrict__ x,
    const short* __restrict__ Wpbf,
    const float* __restrict__ bp, const float* __restrict__ ap,
    const float* __restrict__ gp, const float* __restrict__ betp,
    float* __restrict__ out)
{
    const int t = blockIdx.x;
    const int b = blockIdx.y;
    const int tid = threadIdx.x;
    const int wid = tid >> 6, lane = tid & 63;
    const int g = lane >> 4, c16 = lane & 15;
    const int f_ = tid & 63, cg = tid >> 6;

    __shared__ __align__(16) short wp[64 * 64];
    __shared__ __align__(16) short os[64 * 64];
    __shared__ float zs[64 * 64];
    __shared__ float red[4][2];

#pragma unroll
    for (int j = 0; j < 2; ++j) {
        int i8 = tid + 256 * j;
        int row = i8 >> 3, cb = i8 & 7;
        s16x8 v = *(const s16x8*)(Wpbf + i8 * 8);
        *(s16x8*)&wp[row * 64 + ((cb ^ (row & 7)) * 8)] = v;
    }
#pragma unroll
    for (int it = 0; it < 2; ++it) {
        int cb = cg + 4 * it, c0 = cb * 8;
        s16x8 v;
#pragma unroll
        for (int i = 0; i < 8; ++i)
            v[i] = Ob[(((size_t)b * 64 + c0 + i) * 2048 + t) * 64 + f_];
        *(s16x8*)&os[f_ * 64 + ((cb ^ (f_ & 7)) * 8)] = v;
    }
    __syncthreads();

    const int f0 = wid * 16;
    s16x8 bfr[2];
#pragma unroll
    for (int kk = 0; kk < 2; ++kk)
        bfr[kk] = *(const s16x8*)&os[(f0 + c16) * 64 + (((kk * 4 + g) ^ (c16 & 7)) * 8)];

    const float ap0 = ap[0];
    f32x4 acc[4];
#pragma unroll
    for (int rt = 0; rt < 4; ++rt) {
#pragma unroll
        for (int r = 0; r < 4; ++r) acc[rt][r] = 0.f;
#pragma unroll
        for (int kk = 0; kk < 2; ++kk) {
            s16x8 a = *(const s16x8*)&wp[(rt * 16 + c16) * 64 + (((kk * 4 + g) ^ (c16 & 7)) * 8)];
            acc[rt] = __builtin_amdgcn_mfma_f32_16x16x32_bf16(a, bfr[kk], acc[rt], 0, 0, 0);
        }
    }

#pragma unroll
    for (int rt = 0; rt < 4; ++rt)
#pragma unroll
        for (int r = 0; r < 4; ++r) {
            int row = rt * 16 + g * 4 + r;
            float z = acc[rt][r] + bp[row];
            z = z >= 0.f ? z : ap0 * z;
            zs[row * 64 + f0 + c16] = z;
        }
    __syncthreads();

    float s = 0.f, ss = 0.f;
#pragma unroll
    for (int j = 0; j < 16; ++j) {
        float v = zs[(cg + 4 * j) * 64 + f_];
        s += v; ss += v * v;
    }
#pragma unroll
    for (int msk = 32; msk >= 1; msk >>= 1) {
        s  += __shfl_xor(s, msk);
        ss += __shfl_xor(ss, msk);
    }
    if (lane == 0) { red[wid][0] = s; red[wid][1] = ss; }
    __syncthreads();
    float ts  = red[0][0] + red[1][0] + red[2][0] + red[3][0];
    float tss = red[0][1] + red[1][1] + red[2][1] + red[3][1];
    float mean = ts * (1.f / 4096.f);
    float rstd = rsqrtf(tss * (1.f / 4096.f) - mean * mean + EPS_);

#pragma unroll
    for (int j = 0; j < 16; ++j) {
        int row = cg + 4 * j;
        size_t idx = (((size_t)b * 64 + row) * 2048 + t) * 64 + f_;
        out[idx] = (zs[row * 64 + f_] - mean) * rstd * gp[row * 64 + f_]
                 + betp[row * 64 + f_] + x[idx];
    }
}

// ---------------------------------------------------------------------------
extern "C" void kernel_launch(void* const* d_in, const int* in_sizes, int n_in,
                              void* d_out, int out_size, void* d_ws, size_t ws_size,
                              hipStream_t stream)
{
    const float* x    = (const float*)d_in[0];
    const float* Wq   = (const float*)d_in[1];
    const float* bq   = (const float*)d_in[2];
    const float* aq   = (const float*)d_in[3];
    const float* gq   = (const float*)d_in[4];
    const float* betq = (const float*)d_in[5];
    const float* Wk   = (const float*)d_in[6];
    const float* bk   = (const float*)d_in[7];
    const float* ak   = (const float*)d_in[8];
    const float* gk   = (const float*)d_in[9];
    const float* betk = (const float*)d_in[10];
    const float* Wv   = (const float*)d_in[11];
    const float* bv   = (const float*)d_in[12];
    const float* av   = (const float*)d_in[13];
    const float* gv   = (const float*)d_in[14];
    const float* betv = (const float*)d_in[15];
    const float* Wp   = (const float*)d_in[16];
    const float* bp   = (const float*)d_in[17];
    const float* ap   = (const float*)d_in[18];
    const float* gp   = (const float*)d_in[19];
    const float* betp = (const float*)d_in[20];

    short* Qb   = (short*)d_ws;
    short* Kb   = Qb   + (size_t)8 * 2048 * 256;
    short* Vrm  = Kb   + (size_t)8 * 2048 * 256;
    short* Vt   = Vrm  + (size_t)8 * 2048 * 1024;
    short* Obuf = Vt   + (size_t)8 * 2048 * 1024;
    short* Wbf  = Obuf + (size_t)8 * 2048 * 1024;
    short* Wpbf = Wbf  + 96 * 64;

    prep_kernel<<<40, 256, 0, stream>>>(Wq, Wk, Wv, Wp, Wbf, Wpbf);
    qkv_kernel<<<dim3(2048, 2), 256, 0, stream>>>(x, Wbf,
        bq, aq, gq, betq, bk, ak, gk, betk, bv, av, gv, betv, Qb, Kb, Vrm);
    vtrans_kernel<<<dim3(32, 16, 8), 256, 0, stream>>>(Vrm, Vt);
    attn_kernel<<<dim3(8, 16, 2), 512, 0, stream>>>(Qb, Kb, Vt, Obuf);
    oproj_kernel<<<dim3(2048, 2), 256, 0, stream>>>(Obuf, x, Wpbf,
        bp, ap, gp, betp, (float*)d_out);
}

// Round 11
// 247.544 us; speedup vs baseline: 2.6737x; 1.2526x over previous
//
#include <hip/hip_runtime.h>

#define EPS_ 1e-5f

typedef float f32x4 __attribute__((ext_vector_type(4)));
typedef short s16x8 __attribute__((ext_vector_type(8)));

static __device__ __forceinline__ short f2bf(float f) {
    unsigned u = __float_as_uint(f);
    unsigned r = (u + 0x7FFFu + ((u >> 16) & 1u)) >> 16;
    return (short)r;
}
static __device__ __forceinline__ float bf2f(short s) {
    return __uint_as_float(((unsigned)(unsigned short)s) << 16);
}

// async global->LDS, 16B per lane, wave-uniform LDS base
static __device__ __forceinline__ void gload16(const short* g, short* l) {
    __builtin_amdgcn_global_load_lds(
        (const __attribute__((address_space(1))) unsigned int*)g,
        (__attribute__((address_space(3))) unsigned int*)l, 16, 0, 0);
}

// ---------------------------------------------------------------------------
// Kernel 0: convert weight stacks to bf16 once.
// ---------------------------------------------------------------------------
__global__ __launch_bounds__(256) void prep_kernel(
    const float* __restrict__ Wq, const float* __restrict__ Wk,
    const float* __restrict__ Wv, const float* __restrict__ Wp,
    short* __restrict__ Wbf, short* __restrict__ Wpbf)
{
    int i = blockIdx.x * 256 + threadIdx.x;
    if (i < 6144) {
        float v = (i < 1024) ? Wq[i] : (i < 2048 ? Wk[i - 1024] : Wv[i - 2048]);
        Wbf[i] = f2bf(v);
    } else if (i < 6144 + 4096) {
        Wpbf[i - 6144] = f2bf(Wp[i - 6144]);
    }
}

// ---------------------------------------------------------------------------
// Kernel 1: QKV projection via MFMA + PReLU + LN(chan,freq), write bf16.
// ---------------------------------------------------------------------------
__global__ __launch_bounds__(256) void qkv_kernel(
    const float* __restrict__ x, const short* __restrict__ Wbf,
    const float* __restrict__ bq, const float* __restrict__ aq,
    const float* __restrict__ gq, const float* __restrict__ betq,
    const float* __restrict__ bk, const float* __restrict__ ak,
    const float* __restrict__ gk, const float* __restrict__ betk,
    const float* __restrict__ bv, const float* __restrict__ av,
    const float* __restrict__ gv, const float* __restrict__ betv,
    short* __restrict__ Qo, short* __restrict__ Ko, short* __restrict__ Vo)
{
    const int t = blockIdx.x;
    const int b = blockIdx.y;
    const int tid = threadIdx.x;
    const int wid = tid >> 6, lane = tid & 63;
    const int g = lane >> 4, c16 = lane & 15;
    const int f_ = tid & 63, cg = tid >> 6;

    __shared__ __align__(16) short wlds[96 * 64];
    __shared__ __align__(16) short xs[64 * 64];
    __shared__ float zs[96 * 64];
    __shared__ float stats[12][2];
    __shared__ float bias_l[96], alpha_l[96];

#pragma unroll
    for (int j = 0; j < 3; ++j) {
        int i8 = tid + 256 * j;
        int row = i8 >> 3, cb = i8 & 7;
        s16x8 v = *(const s16x8*)(Wbf + i8 * 8);
        *(s16x8*)&wlds[row * 64 + ((cb ^ (row & 7)) * 8)] = v;
    }
    if (tid < 96) {
        int row = tid; float bias, al;
        if (row < 16)      { bias = bq[row];      al = aq[row >> 2]; }
        else if (row < 32) { bias = bk[row - 16]; al = ak[(row - 16) >> 2]; }
        else               { bias = bv[row - 32]; al = av[(row - 32) >> 4]; }
        bias_l[row] = bias; alpha_l[row] = al;
    }
#pragma unroll
    for (int it = 0; it < 2; ++it) {
        int cb = cg + 4 * it, c0 = cb * 8;
        s16x8 v;
#pragma unroll
        for (int i = 0; i < 8; ++i)
            v[i] = f2bf(x[(((size_t)b * 64 + c0 + i) * 2048 + t) * 64 + f_]);
        *(s16x8*)&xs[f_ * 64 + ((cb ^ (f_ & 7)) * 8)] = v;
    }
    __syncthreads();

    const int f0 = wid * 16;
    s16x8 bfr[2];
#pragma unroll
    for (int kk = 0; kk < 2; ++kk)
        bfr[kk] = *(const s16x8*)&xs[(f0 + c16) * 64 + (((kk * 4 + g) ^ (c16 & 7)) * 8)];

    f32x4 acc[6];
#pragma unroll
    for (int rt = 0; rt < 6; ++rt) {
#pragma unroll
        for (int r = 0; r < 4; ++r) acc[rt][r] = 0.f;
#pragma unroll
        for (int kk = 0; kk < 2; ++kk) {
            s16x8 a = *(const s16x8*)&wlds[(rt * 16 + c16) * 64 + (((kk * 4 + g) ^ (c16 & 7)) * 8)];
            acc[rt] = __builtin_amdgcn_mfma_f32_16x16x32_bf16(a, bfr[kk], acc[rt], 0, 0, 0);
        }
    }

#pragma unroll
    for (int rt = 0; rt < 6; ++rt)
#pragma unroll
        for (int r = 0; r < 4; ++r) {
            int row = rt * 16 + g * 4 + r;
            float z = acc[rt][r] + bias_l[row];
            z = z >= 0.f ? z : alpha_l[row] * z;
            zs[row * 64 + f0 + c16] = z;
        }
    __syncthreads();

#pragma unroll
    for (int gi = 0; gi < 3; ++gi) {
        int grp = wid * 3 + gi;
        int base_row, n;
        if (grp < 4)      { base_row = grp * 4;             n = 256; }
        else if (grp < 8) { base_row = 16 + (grp - 4) * 4;  n = 256; }
        else              { base_row = 32 + (grp - 8) * 16; n = 1024; }
        int cnt = n >> 6;
        float s = 0.f, ss = 0.f;
        for (int i = 0; i < cnt; ++i) {
            float v = zs[(base_row + i) * 64 + lane];
            s += v; ss += v * v;
        }
#pragma unroll
        for (int msk = 32; msk >= 1; msk >>= 1) {
            s  += __shfl_xor(s, msk);
            ss += __shfl_xor(ss, msk);
        }
        if (lane == 0) {
            float mean = s / n;
            float var = ss / n - mean * mean;
            stats[grp][0] = mean;
            stats[grp][1] = rsqrtf(var + EPS_);
        }
    }
    __syncthreads();

#pragma unroll
    for (int j = 0; j < 24; ++j) {
        int row = cg + 4 * j;
        float zv = zs[row * 64 + f_];
        if (row < 16) {
            int grp = row >> 2;
            float val = (zv - stats[grp][0]) * stats[grp][1];
            val = val * gq[row * 64 + f_] + betq[row * 64 + f_];
            int h = row >> 2, o = row & 3;
            Qo[(((size_t)(h * 2 + b)) * 2048 + t) * 256 + o * 64 + f_] = f2bf(val);
        } else if (row < 32) {
            int rr = row - 16, grp = 4 + (rr >> 2);
            float val = (zv - stats[grp][0]) * stats[grp][1];
            val = val * gk[rr * 64 + f_] + betk[rr * 64 + f_];
            int h = rr >> 2, o = rr & 3;
            Ko[(((size_t)(h * 2 + b)) * 2048 + t) * 256 + o * 64 + f_] = f2bf(val);
        } else {
            int rr = row - 32, grp = 8 + (rr >> 4);
            float val = (zv - stats[grp][0]) * stats[grp][1];
            val = val * gv[rr * 64 + f_] + betv[rr * 64 + f_];
            int h = rr >> 4, ov = rr & 15;
            Vo[(((size_t)(h * 2 + b)) * 2048 + t) * 1024 + ov * 64 + f_] = f2bf(val);
        }
    }
}

// ---------------------------------------------------------------------------
// Kernel 2: V row-major [hb][t][d] -> V^T [hb][d][pi(t)] where pi relabels
// keys within each 32-aligned t-block so attn's in-register P (from swapped
// QK^T) feeds PV's A-operand with zero cross-lane movement.
// k' bits (b4 b3 b2 b1 b0) -> phys = b2*16 + b4*8 + b3*4 + b1b0.
// ---------------------------------------------------------------------------
__global__ __launch_bounds__(256) void vtrans_kernel(
    const short* __restrict__ Vrm, short* __restrict__ Vt)
{
    const int t0 = blockIdx.x * 64;
    const int d0 = blockIdx.y * 64;
    const int hb = blockIdx.z;
    const int tid = threadIdx.x;
    __shared__ __align__(16) short tile[64 * 72];

#pragma unroll
    for (int k = 0; k < 2; ++k) {
        int q = tid + 256 * k;
        int row = q >> 3, slot = q & 7;
        s16x8 v = *(const s16x8*)(Vrm + ((size_t)hb * 2048 + t0 + row) * 1024 + d0 + slot * 8);
        *(s16x8*)&tile[row * 72 + slot * 8] = v;
    }
    __syncthreads();
#pragma unroll
    for (int k = 0; k < 2; ++k) {
        int q = tid + 256 * k;
        int drow = q >> 3, tslot = q & 7;
        s16x8 v;
#pragma unroll
        for (int i = 0; i < 8; ++i) {
            int c = tslot * 8 + i;
            int cl = c & 31;
            int src = (c & 32) + ((cl >> 2) & 1) * 16 + ((cl >> 4) & 1) * 8
                    + ((cl >> 3) & 1) * 4 + (cl & 3);
            v[i] = tile[src * 72 + drow];
        }
        *(s16x8*)(Vt + ((size_t)hb * 1024 + d0 + drow) * 2048 + t0 + tslot * 8) = v;
    }
}

// ---------------------------------------------------------------------------
// Kernel 3: flash attention — "DMA-fed, wave-private" structure.
// Grid (8 hb, 16 qt, 2 dh) = 256 blocks, 512 thr (8 waves). QBLK=128
// (wave wq owns q-rows [t0+wq*16,+16) END-TO-END), KBLK=32, 64 k-tiles.
// Swapped QK^T: mfma(A=K, B=Q) -> lane holds S^T[key][q=c16]; softmax fully
// in-register (8 exp + 2 shfl); P packed to the PV A-fragment with zero
// cross-lane movement via the pi key relabeling (V stored pi-permuted).
// K and V both staged to LDS by global_load_lds DMA, double-buffered:
// between barriers the instruction stream is ONLY {ds_read, MFMA, VALU} —
// global latency lives entirely in the async DMA queue, drained at the
// single per-tile barrier. No P-LDS, no cross-wave dependencies.
// LDS: K 2x16KB + V 2x32KB = 96 KB. Regs ~128 AGPR + ~90 VGPR.
// ---------------------------------------------------------------------------
__global__ __launch_bounds__(512, 2) void attn_kernel(
    const short* __restrict__ Qg, const short* __restrict__ Kg,
    const short* __restrict__ Vt, short* __restrict__ Ob)
{
    const int hb = blockIdx.x;     // fast dim -> XCD-affine
    const int qt = blockIdx.y;     // 0..15
    const int dh = blockIdx.z;     // 0..1
    const int t0 = qt * 128;
    const int tid = threadIdx.x;
    const int lane = tid & 63;
    const int wq = tid >> 6;       // wave owns q-rows [t0+wq*16, +16)
    const int g = lane >> 4, c16 = lane & 15;

    __shared__ __align__(16) short k_lds[2][32 * 256];   // 2x16 KB
    __shared__ __align__(16) short v_lds[2][512 * 32];   // 2x32 KB

    const size_t kgbase = (size_t)hb * 2048 * 256;
    const size_t vgbase = ((size_t)hb * 1024 + dh * 512) * 2048;

    // Q B-fragments (col = q = c16, k = kf*32 + g*8 + e), persistent
    const size_t qrow = (size_t)hb * 2048 + t0 + wq * 16 + c16;
    s16x8 qf[8];
#pragma unroll
    for (int kf = 0; kf < 8; ++kf)
        qf[kf] = *(const s16x8*)(Qg + qrow * 256 + kf * 32 + g * 8);

    f32x4 oacc[32];                // [dt]: O[q = g*4+r][d = dt*16 + c16]
#pragma unroll
    for (int i = 0; i < 32; ++i)
#pragma unroll
        for (int r = 0; r < 4; ++r) oacc[i][r] = 0.f;

    float l_r = 0.f;               // softmax denom for q = c16

    // DMA-stage K (32x256, 16KB) and V (512x32, 32KB) tiles: linear LDS dest,
    // inverse-swizzled global source (K: slot^row&7 of 32; V: slot^(row>>1)&3 of 4)
#define STAGE(buf, kt) do {                                                    \
    _Pragma("unroll")                                                          \
    for (int j_ = 0; j_ < 2; ++j_) {                                           \
        int c_ = tid + 512 * j_;                                               \
        int row_ = c_ >> 5, sp_ = c_ & 31;                                     \
        int sl_ = sp_ ^ (row_ & 7);                                            \
        gload16(Kg + kgbase + (size_t)((kt) * 32 + row_) * 256 + sl_ * 8,      \
                &k_lds[buf][c_ * 8]);                                          \
    }                                                                          \
    _Pragma("unroll")                                                          \
    for (int j_ = 0; j_ < 4; ++j_) {                                           \
        int c_ = tid + 512 * j_;                                               \
        int row_ = c_ >> 2, sp_ = c_ & 3;                                      \
        int sl_ = sp_ ^ ((row_ >> 1) & 3);                                     \
        gload16(Vt + vgbase + (size_t)row_ * 2048 + (kt) * 32 + sl_ * 8,       \
                &v_lds[buf][c_ * 8]);                                          \
    }                                                                          \
} while (0)

    // prologue
    STAGE(0, 0);
    __syncthreads();

    for (int t = 0; t < 64; ++t) {
        const int buf = t & 1;

        // issue DMA for tile t+1 into buf^1 (drains during this tile)
        if (t < 63) STAGE(buf ^ 1, t + 1);

        // QK^T swapped: sf[kt2] = S^T[key = kt2*16 + g*4 + r][q = c16]
        f32x4 sf[2];
#pragma unroll
        for (int kt2 = 0; kt2 < 2; ++kt2)
#pragma unroll
            for (int r = 0; r < 4; ++r) sf[kt2][r] = 0.f;
        __builtin_amdgcn_s_setprio(1);
#pragma unroll
        for (int kf = 0; kf < 8; ++kf) {
#pragma unroll
            for (int kt2 = 0; kt2 < 2; ++kt2) {
                int krow = kt2 * 16 + c16;
                s16x8 ka = *(const s16x8*)&k_lds[buf]
                    [krow * 256 + (((kf * 4 + g) ^ (c16 & 7)) * 8)];
                sf[kt2] = __builtin_amdgcn_mfma_f32_16x16x32_bf16(ka, qf[kf], sf[kt2], 0, 0, 0);
            }
        }
        __builtin_amdgcn_s_setprio(0);

        // softmax in-register (no max: Q,K LayerNorm'd): 8 exp + 2 shfl
        float rs = 0.f;
#pragma unroll
        for (int kt2 = 0; kt2 < 2; ++kt2)
#pragma unroll
            for (int r = 0; r < 4; ++r) {
                float p = __expf(sf[kt2][r] * 0.0625f);
                sf[kt2][r] = p;
                rs += p;
            }
        rs += __shfl_xor(rs, 16);
        rs += __shfl_xor(rs, 32);
        l_r += rs;

        // pack P -> PV A-fragment (zero cross-lane; pi absorbs the layout)
        s16x8 pa;
#pragma unroll
        for (int e = 0; e < 8; ++e)
            pa[e] = f2bf(sf[e >> 2][e & 3]);

        // PV: 32 d-tiles x 1 MFMA (K'=32), V from LDS (swizzled, conflict-free)
        __builtin_amdgcn_s_setprio(1);
#pragma unroll
        for (int dt = 0; dt < 32; ++dt) {
            s16x8 vb = *(const s16x8*)&v_lds[buf]
                [(dt * 16 + c16) * 32 + ((g ^ ((c16 >> 1) & 3)) * 8)];
            oacc[dt] = __builtin_amdgcn_mfma_f32_16x16x32_bf16(pa, vb, oacc[dt], 0, 0, 0);
        }
        __builtin_amdgcn_s_setprio(0);

        // single barrier: DMA(t+1) drained; all waves done reading buf
        if (t < 63) __syncthreads();
    }

#undef STAGE

    // epilogue: lane needs l for q = g*4+r (lives in lane with c16 = g*4+r)
    float li[4];
#pragma unroll
    for (int r = 0; r < 4; ++r)
        li[r] = 1.f / __shfl(l_r, g * 4 + r);

    const int h = hb >> 1, b = hb & 1;
#pragma unroll
    for (int dt = 0; dt < 32; ++dt) {
        int vcol = dh * 512 + dt * 16 + c16;
        int cout = h * 16 + (vcol >> 6), ff = vcol & 63;
#pragma unroll
        for (int r = 0; r < 4; ++r) {
            int trow = t0 + wq * 16 + g * 4 + r;
            Ob[(((size_t)b * 64 + cout) * 2048 + trow) * 64 + ff] =
                f2bf(oacc[dt][r] * li[r]);
        }
    }
}

// ---------------------------------------------------------------------------
// Kernel 4: output projection via MFMA + PReLU + LN(C,F) + residual
// ---------------------------------------------------------------------------
__global__ __launch_bounds__(256) void oproj_kernel(
    const short* __restrict__ Ob, const float* __restrict__ x,
    const short* __restrict__ Wpbf,
    const float* __restrict__ bp, const float* __restrict__ ap,
    const float* __restrict__ gp, const float* __restrict__ betp,
    float* __restrict__ out)
{
    const int t = blockIdx.x;
    const int b = blockIdx.y;
    const int tid = threadIdx.x;
    const int wid = tid >> 6, lane = tid & 63;
    const int g = lane >> 4, c16 = lane & 15;
    const int f_ = tid & 63, cg = tid >> 6;

    __shared__ __align__(16) short wp[64 * 64];
    __shared__ __align__(16) short os[64 * 64];
    __shared__ float zs[64 * 64];
    __shared__ float red[4][2];

#pragma unroll
    for (int j = 0; j < 2; ++j) {
        int i8 = tid + 256 * j;
        int row = i8 >> 3, cb = i8 & 7;
        s16x8 v = *(const s16x8*)(Wpbf + i8 * 8);
        *(s16x8*)&wp[row * 64 + ((cb ^ (row & 7)) * 8)] = v;
    }
#pragma unroll
    for (int it = 0; it < 2; ++it) {
        int cb = cg + 4 * it, c0 = cb * 8;
        s16x8 v;
#pragma unroll
        for (int i = 0; i < 8; ++i)
            v[i] = Ob[(((size_t)b * 64 + c0 + i) * 2048 + t) * 64 + f_];
        *(s16x8*)&os[f_ * 64 + ((cb ^ (f_ & 7)) * 8)] = v;
    }
    __syncthreads();

    const int f0 = wid * 16;
    s16x8 bfr[2];
#pragma unroll
    for (int kk = 0; kk < 2; ++kk)
        bfr[kk] = *(const s16x8*)&os[(f0 + c16) * 64 + (((kk * 4 + g) ^ (c16 & 7)) * 8)];

    const float ap0 = ap[0];
    f32x4 acc[4];
#pragma unroll
    for (int rt = 0; rt < 4; ++rt) {
#pragma unroll
        for (int r = 0; r < 4; ++r) acc[rt][r] = 0.f;
#pragma unroll
        for (int kk = 0; kk < 2; ++kk) {
            s16x8 a = *(const s16x8*)&wp[(rt * 16 + c16) * 64 + (((kk * 4 + g) ^ (c16 & 7)) * 8)];
            acc[rt] = __builtin_amdgcn_mfma_f32_16x16x32_bf16(a, bfr[kk], acc[rt], 0, 0, 0);
        }
    }

#pragma unroll
    for (int rt = 0; rt < 4; ++rt)
#pragma unroll
        for (int r = 0; r < 4; ++r) {
            int row = rt * 16 + g * 4 + r;
            float z = acc[rt][r] + bp[row];
            z = z >= 0.f ? z : ap0 * z;
            zs[row * 64 + f0 + c16] = z;
        }
    __syncthreads();

    float s = 0.f, ss = 0.f;
#pragma unroll
    for (int j = 0; j < 16; ++j) {
        float v = zs[(cg + 4 * j) * 64 + f_];
        s += v; ss += v * v;
    }
#pragma unroll
    for (int msk = 32; msk >= 1; msk >>= 1) {
        s  += __shfl_xor(s, msk);
        ss += __shfl_xor(ss, msk);
    }
    if (lane == 0) { red[wid][0] = s; red[wid][1] = ss; }
    __syncthreads();
    float ts  = red[0][0] + red[1][0] + red[2][0] + red[3][0];
    float tss = red[0][1] + red[1][1] + red[2][1] + red[3][1];
    float mean = ts * (1.f / 4096.f);
    float rstd = rsqrtf(tss * (1.f / 4096.f) - mean * mean + EPS_);

#pragma unroll
    for (int j = 0; j < 16; ++j) {
        int row = cg + 4 * j;
        size_t idx = (((size_t)b * 64 + row) * 2048 + t) * 64 + f_;
        out[idx] = (zs[row * 64 + f_] - mean) * rstd * gp[row * 64 + f_]
                 + betp[row * 64 + f_] + x[idx];
    }
}

// ---------------------------------------------------------------------------
extern "C" void kernel_launch(void* const* d_in, const int* in_sizes, int n_in,
                              void* d_out, int out_size, void* d_ws, size_t ws_size,
                              hipStream_t stream)
{
    const float* x    = (const float*)d_in[0];
    const float* Wq   = (const float*)d_in[1];
    const float* bq   = (const float*)d_in[2];
    const float* aq   = (const float*)d_in[3];
    const float* gq   = (const float*)d_in[4];
    const float* betq = (const float*)d_in[5];
    const float* Wk   = (const float*)d_in[6];
    const float* bk   = (const float*)d_in[7];
    const float* ak   = (const float*)d_in[8];
    const float* gk   = (const float*)d_in[9];
    const float* betk = (const float*)d_in[10];
    const float* Wv   = (const float*)d_in[11];
    const float* bv   = (const float*)d_in[12];
    const float* av   = (const float*)d_in[13];
    const float* gv   = (const float*)d_in[14];
    const float* betv = (const float*)d_in[15];
    const float* Wp   = (const float*)d_in[16];
    const float* bp   = (const float*)d_in[17];
    const float* ap   = (const float*)d_in[18];
    const float* gp   = (const float*)d_in[19];
    const float* betp = (const float*)d_in[20];

    short* Qb   = (short*)d_ws;
    short* Kb   = Qb   + (size_t)8 * 2048 * 256;
    short* Vrm  = Kb   + (size_t)8 * 2048 * 256;
    short* Vt   = Vrm  + (size_t)8 * 2048 * 1024;
    short* Obuf = Vt   + (size_t)8 * 2048 * 1024;
    short* Wbf  = Obuf + (size_t)8 * 2048 * 1024;
    short* Wpbf = Wbf  + 96 * 64;

    prep_kernel<<<40, 256, 0, stream>>>(Wq, Wk, Wv, Wp, Wbf, Wpbf);
    qkv_kernel<<<dim3(2048, 2), 256, 0, stream>>>(x, Wbf,
        bq, aq, gq, betq, bk, ak, gk, betk, bv, av, gv, betv, Qb, Kb, Vrm);
    vtrans_kernel<<<dim3(32, 16, 8), 256, 0, stream>>>(Vrm, Vt);
    attn_kernel<<<dim3(8, 16, 2), 512, 0, stream>>>(Qb, Kb, Vt, Obuf);
    oproj_kernel<<<dim3(2048, 2), 256, 0, stream>>>(Obuf, x, Wpbf,
        bp, ap, gp, betp, (float*)d_out);
}